// Round 5
// baseline (57.696 us; speedup 1.0000x reference)
//
#include <hip/hip_runtime.h>

#define CLS 64
#define DIM 128
#define NROWS 262144
#define MARGIN 1.4f
#define EPSF 1e-6f
#define FIXSCALE 1048576.0f        // 2^20 (sum fixed point)
#define INVFIX (1.0f / 1048576.0f)
#define SQSCALE 1048576.0          // 2^20 (sumsq fixed point, u64)
#define INVSQ (1.0 / 1048576.0)
#define NB 256                     // one 1024-thread block per CU

// ---------------- zero kernel: re-init global accumulators every call ----------------
__global__ __launch_bounds__(256) void zeroK(int* __restrict__ p, int n) {
    int i = blockIdx.x * 256 + threadIdx.x;
    if (i < n) p[i] = 0;
}

// ---------------- Phase A: LDS int accumulation -> staggered global int atomics ----------------
__global__ __launch_bounds__(1024, 1) void phaseA(const float* __restrict__ emb,
                                                  const int* __restrict__ tgt,
                                                  int* __restrict__ fsum_i,
                                                  int* __restrict__ fcnt_i,
                                                  unsigned long long* __restrict__ sq64,
                                                  int rowsPerBlock) {
    __shared__ int acc[CLS * DIM];
    __shared__ int cnt[CLS];
    __shared__ float red[16];
    const int tid = threadIdx.x;

    for (int i = tid; i < CLS * DIM; i += 1024) acc[i] = 0;
    if (tid < CLS) cnt[tid] = 0;
    __syncthreads();

    const int dl = tid & 31;               // dim-lane (covers 4 dims via float4)
    const int rl = tid >> 5;               // row-lane 0..31
    const int rowBase = blockIdx.x * rowsPerBlock;
    const int iters = rowsPerBlock >> 7;   // 128 rows per iteration
    int r = rowBase + rl;

    const float4* __restrict__ embv = reinterpret_cast<const float4*>(emb);

    // 4-deep prefetch: rows r, r+32, r+64, r+96
    float4 v0 = embv[(size_t)(r)      * 32 + dl];
    float4 v1 = embv[(size_t)(r + 32) * 32 + dl];
    float4 v2 = embv[(size_t)(r + 64) * 32 + dl];
    float4 v3 = embv[(size_t)(r + 96) * 32 + dl];
    int c0 = tgt[r];
    int c1 = tgt[r + 32];
    int c2 = tgt[r + 64];
    int c3 = tgt[r + 96];

    float sq = 0.f;
    for (int it = 0; it < iters; ++it) {
        float4 x0 = v0, x1 = v1, x2 = v2, x3 = v3;
        int k0 = c0, k1 = c1, k2 = c2, k3 = c3;
        int rn = r + 128;
        if (it + 1 < iters) {
            v0 = embv[(size_t)(rn)      * 32 + dl];
            v1 = embv[(size_t)(rn + 32) * 32 + dl];
            v2 = embv[(size_t)(rn + 64) * 32 + dl];
            v3 = embv[(size_t)(rn + 96) * 32 + dl];
            c0 = tgt[rn];
            c1 = tgt[rn + 32];
            c2 = tgt[rn + 64];
            c3 = tgt[rn + 96];
        }
        r = rn;

        sq += x0.x * x0.x + x0.y * x0.y + x0.z * x0.z + x0.w * x0.w;
        sq += x1.x * x1.x + x1.y * x1.y + x1.z * x1.z + x1.w * x1.w;
        sq += x2.x * x2.x + x2.y * x2.y + x2.z * x2.z + x2.w * x2.w;
        sq += x3.x * x3.x + x3.y * x3.y + x3.z * x3.z + x3.w * x3.w;

        int* row0 = &acc[k0 * DIM];
        atomicAdd(&row0[dl],      __float2int_rn(x0.x * FIXSCALE));
        atomicAdd(&row0[32 + dl], __float2int_rn(x0.y * FIXSCALE));
        atomicAdd(&row0[64 + dl], __float2int_rn(x0.z * FIXSCALE));
        atomicAdd(&row0[96 + dl], __float2int_rn(x0.w * FIXSCALE));
        int* row1 = &acc[k1 * DIM];
        atomicAdd(&row1[dl],      __float2int_rn(x1.x * FIXSCALE));
        atomicAdd(&row1[32 + dl], __float2int_rn(x1.y * FIXSCALE));
        atomicAdd(&row1[64 + dl], __float2int_rn(x1.z * FIXSCALE));
        atomicAdd(&row1[96 + dl], __float2int_rn(x1.w * FIXSCALE));
        int* row2 = &acc[k2 * DIM];
        atomicAdd(&row2[dl],      __float2int_rn(x2.x * FIXSCALE));
        atomicAdd(&row2[32 + dl], __float2int_rn(x2.y * FIXSCALE));
        atomicAdd(&row2[64 + dl], __float2int_rn(x2.z * FIXSCALE));
        atomicAdd(&row2[96 + dl], __float2int_rn(x2.w * FIXSCALE));
        int* row3 = &acc[k3 * DIM];
        atomicAdd(&row3[dl],      __float2int_rn(x3.x * FIXSCALE));
        atomicAdd(&row3[32 + dl], __float2int_rn(x3.y * FIXSCALE));
        atomicAdd(&row3[64 + dl], __float2int_rn(x3.z * FIXSCALE));
        atomicAdd(&row3[96 + dl], __float2int_rn(x3.w * FIXSCALE));
        if (dl == 0) {
            atomicAdd(&cnt[k0], 1);
            atomicAdd(&cnt[k1], 1);
            atomicAdd(&cnt[k2], 1);
            atomicAdd(&cnt[k3], 1);
        }
    }

    // wave reduce sumsq, then block reduce via LDS
    for (int o = 32; o > 0; o >>= 1) sq += __shfl_down(sq, o, 64);
    if ((tid & 63) == 0) red[tid >> 6] = sq;
    __syncthreads();

    // staggered flush: each block starts at a different 128B cache line so the
    // 2.1M device atomics spread across all 512 lines at every instant
    const int rot = (blockIdx.x & 255) * 32;
    for (int i = tid; i < CLS * DIM; i += 1024) {
        const int j = (i + rot) & (CLS * DIM - 1);
        atomicAdd(&fsum_i[j], acc[j]);
    }
    if (tid < CLS) atomicAdd(&fcnt_i[(tid + rot) & (CLS - 1)], cnt[(tid + rot) & (CLS - 1)]);
    if (tid == 0) {
        double s = 0.0;
        for (int k = 0; k < 16; ++k) s += (double)red[k];
        atomicAdd(sq64, (unsigned long long)(s * SQSCALE + 0.5));
    }
}

// ---------------- Phase C: centers, l2 identity, pairwise margin via Gram ----------------
__device__ double blockReduceD(double v, double* scratch, int tid) {
    for (int o = 32; o > 0; o >>= 1) v += __shfl_down(v, o, 64);
    if ((tid & 63) == 0) scratch[tid >> 6] = v;
    __syncthreads();
    double t = 0.0;
    if (tid == 0) {
        for (int i = 0; i < 16; ++i) t += scratch[i];
    }
    __syncthreads();
    return t;
}

__global__ __launch_bounds__(1024) void phaseC(const int* __restrict__ fsum_i,
                                               const int* __restrict__ fcnt_i,
                                               const unsigned long long* __restrict__ sq64,
                                               float* __restrict__ out) {
    __shared__ float cenT[DIM][CLS];   // transposed centers: conflict-free column access
    __shared__ float nrm[CLS];
    __shared__ float cInv[CLS];
    __shared__ float cRaw[CLS];
    __shared__ double scratch[16];
    const int tid = threadIdx.x;

    if (tid < CLS) {
        float c = (float)fcnt_i[tid];
        cRaw[tid] = c;
        cInv[tid] = 1.f / (c + EPSF);
    }
    __syncthreads();

    double s1 = 0.0, s2 = 0.0;
    for (int i = tid; i < CLS * DIM; i += 1024) {
        const int c = i >> 7;
        const int d = i & 127;
        float v = (float)fsum_i[i] * INVFIX;
        float ctr = v * cInv[c];
        cenT[d][c] = ctr;
        s1 += (double)(v * ctr);
        s2 += (double)(cRaw[c] * ctr * ctr);
    }
    const double s1t = blockReduceD(s1, scratch, tid);   // internal syncs make cenT visible
    const double s2t = blockReduceD(s2, scratch, tid);

    // per-class squared norms
    if (tid < CLS) {
        float n = 0.f;
        for (int d = 0; d < DIM; ++d) {
            float v = cenT[d][tid];
            n += v * v;
        }
        nrm[tid] = n;
    }
    __syncthreads();

    // Gram: wave w handles rows a = w, w+16, w+32, w+48 against all b = lane
    const int w = tid >> 6;
    const int b = tid & 63;
    float g0 = 0.f, g1 = 0.f, g2 = 0.f, g3 = 0.f;
    for (int d = 0; d < DIM; ++d) {
        float vb = cenT[d][b];               // coalesced, conflict-free
        g0 += cenT[d][w]      * vb;          // wave-uniform -> broadcast
        g1 += cenT[d][w + 16] * vb;
        g2 += cenT[d][w + 32] * vb;
        g3 += cenT[d][w + 48] * vb;
    }
    float ccp = 0.f;
    {
        float gs[4] = {g0, g1, g2, g3};
#pragma unroll
        for (int j = 0; j < 4; ++j) {
            const int a = w + 16 * j;
            if (a == b) continue;
            float d2 = nrm[a] + nrm[b] - 2.f * gs[j];
            float val = fmaxf(MARGIN - sqrtf(fmaxf(d2, 0.f) + EPSF), 0.f);
            ccp += val * val;
        }
    }
    const double ccOrd = blockReduceD((double)ccp, scratch, tid);

    if (tid == 0) {
        double triu = ccOrd * 0.5;                     // ordered pairs -> a<b
        double ccv = triu / 64.0 * 63.0 / 2.0;
        double fsq = (double)sq64[0] * INVSQ;
        double l2 = (fsq - 2.0 * s1t + s2t) / (double)NROWS;
        out[0] = (float)(l2 + ccv);
    }
}

extern "C" void kernel_launch(void* const* d_in, const int* in_sizes, int n_in,
                              void* d_out, int out_size, void* d_ws, size_t ws_size,
                              hipStream_t stream) {
    const float* emb = (const float*)d_in[0];
    const int* tgt = (const int*)d_in[1];
    float* out = (float*)d_out;

    char* ws = (char*)d_ws;
    int* fsum_i = (int*)ws;                                  // 8192 ints
    int* fcnt_i = fsum_i + CLS * DIM;                        // 64 ints
    unsigned long long* sq64 = (unsigned long long*)(ws + 33024); // 8B, aligned

    const int nZero = CLS * DIM + CLS + 2;                   // 8258 dwords
    const int rowsPerBlock = NROWS / NB;                     // 1024

    zeroK<<<(nZero + 255) / 256, 256, 0, stream>>>(fsum_i, nZero);
    phaseA<<<NB, 1024, 0, stream>>>(emb, tgt, fsum_i, fcnt_i, sq64, rowsPerBlock);
    phaseC<<<1, 1024, 0, stream>>>(fsum_i, fcnt_i, sq64, out);
}

// Round 6
// 55.377 us; speedup vs baseline: 1.0419x; 1.0419x over previous
//
#include <hip/hip_runtime.h>

#define CLS 64
#define DIM 128
#define NROWS 262144
#define MARGIN 1.4f
#define EPSF 1e-6f
#define FIXSCALE 1048576.0f        // 2^20 (LDS sum fixed point)
#define INVFIX (1.0f / 1048576.0f)
#define NB 512                     // 2 blocks/CU, 512 threads each

// ---------------- Phase A: LDS int accumulation -> private per-block partials ----------------
__global__ __launch_bounds__(512, 2) void phaseA(const float* __restrict__ emb,
                                                 const int* __restrict__ tgt,
                                                 float* __restrict__ psum,
                                                 int* __restrict__ pcnt,
                                                 float* __restrict__ psq,
                                                 int rowsPerBlock) {
    __shared__ int acc[CLS * DIM];
    __shared__ int cnt[CLS];
    __shared__ float red[8];
    const int tid = threadIdx.x;

    for (int i = tid; i < CLS * DIM; i += 512) acc[i] = 0;
    if (tid < CLS) cnt[tid] = 0;
    __syncthreads();

    const int dl = tid & 31;               // dim-lane (covers 4 dims via float4)
    const int rl = tid >> 5;               // row-lane 0..15
    const int rowBase = blockIdx.x * rowsPerBlock;
    const int iters = rowsPerBlock >> 6;   // 64 rows per iteration
    int r = rowBase + rl;

    const float4* __restrict__ embv = reinterpret_cast<const float4*>(emb);

    // 4-deep prefetch: rows r, r+16, r+32, r+48
    float4 v0 = embv[(size_t)(r)      * 32 + dl];
    float4 v1 = embv[(size_t)(r + 16) * 32 + dl];
    float4 v2 = embv[(size_t)(r + 32) * 32 + dl];
    float4 v3 = embv[(size_t)(r + 48) * 32 + dl];
    int c0 = tgt[r];
    int c1 = tgt[r + 16];
    int c2 = tgt[r + 32];
    int c3 = tgt[r + 48];

    float sq = 0.f;
    for (int it = 0; it < iters; ++it) {
        float4 x0 = v0, x1 = v1, x2 = v2, x3 = v3;
        int k0 = c0, k1 = c1, k2 = c2, k3 = c3;
        int rn = r + 64;
        if (it + 1 < iters) {
            v0 = embv[(size_t)(rn)      * 32 + dl];
            v1 = embv[(size_t)(rn + 16) * 32 + dl];
            v2 = embv[(size_t)(rn + 32) * 32 + dl];
            v3 = embv[(size_t)(rn + 48) * 32 + dl];
            c0 = tgt[rn];
            c1 = tgt[rn + 16];
            c2 = tgt[rn + 32];
            c3 = tgt[rn + 48];
        }
        r = rn;

        sq += x0.x * x0.x + x0.y * x0.y + x0.z * x0.z + x0.w * x0.w;
        sq += x1.x * x1.x + x1.y * x1.y + x1.z * x1.z + x1.w * x1.w;
        sq += x2.x * x2.x + x2.y * x2.y + x2.z * x2.z + x2.w * x2.w;
        sq += x3.x * x3.x + x3.y * x3.y + x3.z * x3.z + x3.w * x3.w;

        int* row0 = &acc[k0 * DIM];
        atomicAdd(&row0[dl],      __float2int_rn(x0.x * FIXSCALE));
        atomicAdd(&row0[32 + dl], __float2int_rn(x0.y * FIXSCALE));
        atomicAdd(&row0[64 + dl], __float2int_rn(x0.z * FIXSCALE));
        atomicAdd(&row0[96 + dl], __float2int_rn(x0.w * FIXSCALE));
        int* row1 = &acc[k1 * DIM];
        atomicAdd(&row1[dl],      __float2int_rn(x1.x * FIXSCALE));
        atomicAdd(&row1[32 + dl], __float2int_rn(x1.y * FIXSCALE));
        atomicAdd(&row1[64 + dl], __float2int_rn(x1.z * FIXSCALE));
        atomicAdd(&row1[96 + dl], __float2int_rn(x1.w * FIXSCALE));
        int* row2 = &acc[k2 * DIM];
        atomicAdd(&row2[dl],      __float2int_rn(x2.x * FIXSCALE));
        atomicAdd(&row2[32 + dl], __float2int_rn(x2.y * FIXSCALE));
        atomicAdd(&row2[64 + dl], __float2int_rn(x2.z * FIXSCALE));
        atomicAdd(&row2[96 + dl], __float2int_rn(x2.w * FIXSCALE));
        int* row3 = &acc[k3 * DIM];
        atomicAdd(&row3[dl],      __float2int_rn(x3.x * FIXSCALE));
        atomicAdd(&row3[32 + dl], __float2int_rn(x3.y * FIXSCALE));
        atomicAdd(&row3[64 + dl], __float2int_rn(x3.z * FIXSCALE));
        atomicAdd(&row3[96 + dl], __float2int_rn(x3.w * FIXSCALE));
        if (dl == 0) {
            atomicAdd(&cnt[k0], 1);
            atomicAdd(&cnt[k1], 1);
            atomicAdd(&cnt[k2], 1);
            atomicAdd(&cnt[k3], 1);
        }
    }

    // wave reduce sumsq, then block reduce via LDS
    for (int o = 32; o > 0; o >>= 1) sq += __shfl_down(sq, o, 64);
    if ((tid & 63) == 0) red[tid >> 6] = sq;
    __syncthreads();

    // non-atomic flush to this block's private partial slot (coalesced float4 stores)
    float4* __restrict__ pv = reinterpret_cast<float4*>(psum + (size_t)blockIdx.x * (CLS * DIM));
    const int4* __restrict__ av = reinterpret_cast<const int4*>(acc);
    for (int i = tid; i < (CLS * DIM) / 4; i += 512) {
        int4 a = av[i];
        pv[i] = make_float4((float)a.x * INVFIX, (float)a.y * INVFIX,
                            (float)a.z * INVFIX, (float)a.w * INVFIX);
    }
    if (tid < CLS) pcnt[blockIdx.x * CLS + tid] = cnt[tid];
    if (tid == 0) {
        float s = 0.f;
        for (int k = 0; k < 8; ++k) s += red[k];
        psq[blockIdx.x] = s;
    }
}

// ---------------- Phase B: deterministic partials reduction ----------------
// blocks 0..127: 64 dims each, 4 k-chunks of 128; block 128: counts + sumsq
__global__ __launch_bounds__(256) void phaseBR(const float* __restrict__ psum,
                                               const int* __restrict__ pcnt,
                                               const float* __restrict__ psq,
                                               float* __restrict__ fsum,
                                               int* __restrict__ fcnt,
                                               double* __restrict__ fsq) {
    const int tid = threadIdx.x;
    if (blockIdx.x < 128) {
        const int o = blockIdx.x * 64 + (tid & 63);
        const int q = tid >> 6;                       // k-quarter 0..3
        const float* __restrict__ p = psum + (size_t)q * 128 * (CLS * DIM) + o;
        float s0 = 0.f, s1 = 0.f, s2 = 0.f, s3 = 0.f;
        for (int j = 0; j < 128; j += 4) {
            s0 += p[(size_t)(j)     * (CLS * DIM)];
            s1 += p[(size_t)(j + 1) * (CLS * DIM)];
            s2 += p[(size_t)(j + 2) * (CLS * DIM)];
            s3 += p[(size_t)(j + 3) * (CLS * DIM)];
        }
        __shared__ float sh[4][64];
        sh[q][tid & 63] = (s0 + s1) + (s2 + s3);
        __syncthreads();
        if (tid < 64) fsum[o] = (sh[0][tid] + sh[1][tid]) + (sh[2][tid] + sh[3][tid]);
    } else {
        // counts: 64 outputs x NB partials
        const int c = tid & 63;
        const int q = tid >> 6;                       // 0..3
        int s = 0;
        for (int k = q * (NB / 4); k < (q + 1) * (NB / 4); ++k) s += pcnt[k * CLS + c];
        __shared__ int shc[4][64];
        shc[q][c] = s;
        __syncthreads();
        if (tid < 64) fcnt[tid] = (shc[0][tid] + shc[1][tid]) + (shc[2][tid] + shc[3][tid]);
        // sumsq: NB values, double, fixed order within lane then shuffle tree
        if (tid < 64) {
            double d = 0.0;
            for (int k = tid; k < NB; k += 64) d += (double)psq[k];
            for (int o2 = 32; o2 > 0; o2 >>= 1) d += __shfl_down(d, o2, 64);
            if (tid == 0) fsq[0] = d;
        }
    }
}

// ---------------- Phase C: centers, l2 identity, pairwise margin via Gram ----------------
__device__ double blockReduceD(double v, double* scratch, int tid) {
    for (int o = 32; o > 0; o >>= 1) v += __shfl_down(v, o, 64);
    if ((tid & 63) == 0) scratch[tid >> 6] = v;
    __syncthreads();
    double t = 0.0;
    if (tid == 0) {
        for (int i = 0; i < 16; ++i) t += scratch[i];
    }
    __syncthreads();
    return t;
}

__global__ __launch_bounds__(1024) void phaseC(const float* __restrict__ fsum,
                                               const int* __restrict__ fcnt,
                                               const double* __restrict__ fsq,
                                               float* __restrict__ out) {
    __shared__ float cenT[DIM][CLS];   // transposed centers: conflict-free column access
    __shared__ float nrm[CLS];
    __shared__ float cInv[CLS];
    __shared__ float cRaw[CLS];
    __shared__ double scratch[16];
    const int tid = threadIdx.x;

    if (tid < CLS) {
        float c = (float)fcnt[tid];
        cRaw[tid] = c;
        cInv[tid] = 1.f / (c + EPSF);
    }
    __syncthreads();

    double s1 = 0.0, s2 = 0.0;
    for (int i = tid; i < CLS * DIM; i += 1024) {
        const int c = i >> 7;
        const int d = i & 127;
        float v = fsum[i];
        float ctr = v * cInv[c];
        cenT[d][c] = ctr;
        s1 += (double)(v * ctr);
        s2 += (double)(cRaw[c] * ctr * ctr);
    }
    const double s1t = blockReduceD(s1, scratch, tid);   // internal syncs make cenT visible
    const double s2t = blockReduceD(s2, scratch, tid);

    // per-class squared norms
    if (tid < CLS) {
        float n = 0.f;
        for (int d = 0; d < DIM; ++d) {
            float v = cenT[d][tid];
            n += v * v;
        }
        nrm[tid] = n;
    }
    __syncthreads();

    // Gram: wave w handles rows a = w, w+16, w+32, w+48 against all b = lane
    const int w = tid >> 6;
    const int b = tid & 63;
    float g0 = 0.f, g1 = 0.f, g2 = 0.f, g3 = 0.f;
    for (int d = 0; d < DIM; ++d) {
        float vb = cenT[d][b];               // coalesced, conflict-free
        g0 += cenT[d][w]      * vb;          // wave-uniform -> broadcast
        g1 += cenT[d][w + 16] * vb;
        g2 += cenT[d][w + 32] * vb;
        g3 += cenT[d][w + 48] * vb;
    }
    float ccp = 0.f;
    {
        float gs[4] = {g0, g1, g2, g3};
#pragma unroll
        for (int j = 0; j < 4; ++j) {
            const int a = w + 16 * j;
            if (a == b) continue;
            float d2 = nrm[a] + nrm[b] - 2.f * gs[j];
            float val = fmaxf(MARGIN - sqrtf(fmaxf(d2, 0.f) + EPSF), 0.f);
            ccp += val * val;
        }
    }
    const double ccOrd = blockReduceD((double)ccp, scratch, tid);

    if (tid == 0) {
        double triu = ccOrd * 0.5;                     // ordered pairs -> a<b
        double ccv = triu / 64.0 * 63.0 / 2.0;
        double l2 = (fsq[0] - 2.0 * s1t + s2t) / (double)NROWS;
        out[0] = (float)(l2 + ccv);
    }
}

extern "C" void kernel_launch(void* const* d_in, const int* in_sizes, int n_in,
                              void* d_out, int out_size, void* d_ws, size_t ws_size,
                              hipStream_t stream) {
    const float* emb = (const float*)d_in[0];
    const int* tgt = (const int*)d_in[1];
    float* out = (float*)d_out;

    char* ws = (char*)d_ws;
    float* fsum = (float*)ws;                          // 8192 floats  @ 0
    int* fcnt = (int*)(ws + 32768);                    // 64 ints      @ 32768
    double* fsq = (double*)(ws + 33024);               // 1 double     @ 33024 (8-aligned)
    float* psum = (float*)(ws + 65536);                // NB*8192 floats (16 MB)
    int* pcnt = (int*)(ws + 65536 + (size_t)NB * CLS * DIM * 4);   // NB*64 ints
    float* psq = (float*)(ws + 65536 + (size_t)NB * CLS * DIM * 4 + (size_t)NB * CLS * 4); // NB floats

    const int rowsPerBlock = NROWS / NB;               // 512

    phaseA<<<NB, 512, 0, stream>>>(emb, tgt, psum, pcnt, psq, rowsPerBlock);
    phaseBR<<<129, 256, 0, stream>>>(psum, pcnt, psq, fsum, fcnt, fsq);
    phaseC<<<1, 1024, 0, stream>>>(fsum, fcnt, fsq, out);
}

// Round 7
// 54.743 us; speedup vs baseline: 1.0539x; 1.0116x over previous
//
#include <hip/hip_runtime.h>

#define CLS 64
#define DIM 128
#define NROWS 262144
#define MARGIN 1.4f
#define EPSF 1e-6f
#define FIXSCALE 1048576.0f        // 2^20 (LDS sum fixed point)
#define INVFIX (1.0f / 1048576.0f)
#define NB 512                     // 2 blocks/CU, 1024 threads each -> 32 waves/CU

// ---------------- Phase A: LDS int accumulation -> private per-block partials ----------------
__global__ __launch_bounds__(1024, 2) void phaseA(const float* __restrict__ emb,
                                                  const int* __restrict__ tgt,
                                                  float* __restrict__ psum,
                                                  int* __restrict__ pcnt,
                                                  float* __restrict__ psq,
                                                  int rowsPerBlock) {
    __shared__ int acc[CLS * DIM];
    __shared__ int cnt[CLS];
    __shared__ float red[16];
    const int tid = threadIdx.x;

    for (int i = tid; i < CLS * DIM; i += 1024) acc[i] = 0;
    if (tid < CLS) cnt[tid] = 0;
    __syncthreads();

    const int dl = tid & 31;               // dim-lane (covers 4 dims via float4)
    const int rl = tid >> 5;               // row-lane 0..31
    const int rowBase = blockIdx.x * rowsPerBlock;
    const int iters = rowsPerBlock >> 7;   // 128 rows per iteration
    int r = rowBase + rl;

    const float4* __restrict__ embv = reinterpret_cast<const float4*>(emb);

    // 4-deep prefetch: rows r, r+32, r+64, r+96
    float4 v0 = embv[(size_t)(r)      * 32 + dl];
    float4 v1 = embv[(size_t)(r + 32) * 32 + dl];
    float4 v2 = embv[(size_t)(r + 64) * 32 + dl];
    float4 v3 = embv[(size_t)(r + 96) * 32 + dl];
    int c0 = tgt[r];
    int c1 = tgt[r + 32];
    int c2 = tgt[r + 64];
    int c3 = tgt[r + 96];

    float sq = 0.f;
    for (int it = 0; it < iters; ++it) {
        float4 x0 = v0, x1 = v1, x2 = v2, x3 = v3;
        int k0 = c0, k1 = c1, k2 = c2, k3 = c3;
        int rn = r + 128;
        if (it + 1 < iters) {
            v0 = embv[(size_t)(rn)      * 32 + dl];
            v1 = embv[(size_t)(rn + 32) * 32 + dl];
            v2 = embv[(size_t)(rn + 64) * 32 + dl];
            v3 = embv[(size_t)(rn + 96) * 32 + dl];
            c0 = tgt[rn];
            c1 = tgt[rn + 32];
            c2 = tgt[rn + 64];
            c3 = tgt[rn + 96];
        }
        r = rn;

        sq += x0.x * x0.x + x0.y * x0.y + x0.z * x0.z + x0.w * x0.w;
        sq += x1.x * x1.x + x1.y * x1.y + x1.z * x1.z + x1.w * x1.w;
        sq += x2.x * x2.x + x2.y * x2.y + x2.z * x2.z + x2.w * x2.w;
        sq += x3.x * x3.x + x3.y * x3.y + x3.z * x3.z + x3.w * x3.w;

        int* row0 = &acc[k0 * DIM];
        atomicAdd(&row0[dl],      __float2int_rn(x0.x * FIXSCALE));
        atomicAdd(&row0[32 + dl], __float2int_rn(x0.y * FIXSCALE));
        atomicAdd(&row0[64 + dl], __float2int_rn(x0.z * FIXSCALE));
        atomicAdd(&row0[96 + dl], __float2int_rn(x0.w * FIXSCALE));
        int* row1 = &acc[k1 * DIM];
        atomicAdd(&row1[dl],      __float2int_rn(x1.x * FIXSCALE));
        atomicAdd(&row1[32 + dl], __float2int_rn(x1.y * FIXSCALE));
        atomicAdd(&row1[64 + dl], __float2int_rn(x1.z * FIXSCALE));
        atomicAdd(&row1[96 + dl], __float2int_rn(x1.w * FIXSCALE));
        int* row2 = &acc[k2 * DIM];
        atomicAdd(&row2[dl],      __float2int_rn(x2.x * FIXSCALE));
        atomicAdd(&row2[32 + dl], __float2int_rn(x2.y * FIXSCALE));
        atomicAdd(&row2[64 + dl], __float2int_rn(x2.z * FIXSCALE));
        atomicAdd(&row2[96 + dl], __float2int_rn(x2.w * FIXSCALE));
        int* row3 = &acc[k3 * DIM];
        atomicAdd(&row3[dl],      __float2int_rn(x3.x * FIXSCALE));
        atomicAdd(&row3[32 + dl], __float2int_rn(x3.y * FIXSCALE));
        atomicAdd(&row3[64 + dl], __float2int_rn(x3.z * FIXSCALE));
        atomicAdd(&row3[96 + dl], __float2int_rn(x3.w * FIXSCALE));
        if (dl == 0) {
            atomicAdd(&cnt[k0], 1);
            atomicAdd(&cnt[k1], 1);
            atomicAdd(&cnt[k2], 1);
            atomicAdd(&cnt[k3], 1);
        }
    }

    // wave reduce sumsq, then block reduce via LDS
    for (int o = 32; o > 0; o >>= 1) sq += __shfl_down(sq, o, 64);
    if ((tid & 63) == 0) red[tid >> 6] = sq;
    __syncthreads();

    // non-atomic flush to this block's private partial slot (coalesced float4 stores)
    float4* __restrict__ pv = reinterpret_cast<float4*>(psum + (size_t)blockIdx.x * (CLS * DIM));
    const int4* __restrict__ av = reinterpret_cast<const int4*>(acc);
    for (int i = tid; i < (CLS * DIM) / 4; i += 1024) {
        int4 a = av[i];
        pv[i] = make_float4((float)a.x * INVFIX, (float)a.y * INVFIX,
                            (float)a.z * INVFIX, (float)a.w * INVFIX);
    }
    if (tid < CLS) pcnt[blockIdx.x * CLS + tid] = cnt[tid];
    if (tid == 0) {
        float s = 0.f;
        for (int k = 0; k < 16; ++k) s += red[k];
        psq[blockIdx.x] = s;
    }
}

// ---------------- Phase B: deterministic partials reduction ----------------
// blocks 0..127: 64 dims each, 4 k-chunks of 128; block 128: counts + sumsq
__global__ __launch_bounds__(256) void phaseBR(const float* __restrict__ psum,
                                               const int* __restrict__ pcnt,
                                               const float* __restrict__ psq,
                                               float* __restrict__ fsum,
                                               int* __restrict__ fcnt,
                                               double* __restrict__ fsq) {
    const int tid = threadIdx.x;
    if (blockIdx.x < 128) {
        const int o = blockIdx.x * 64 + (tid & 63);
        const int q = tid >> 6;                       // k-quarter 0..3
        const float* __restrict__ p = psum + (size_t)q * 128 * (CLS * DIM) + o;
        float s0 = 0.f, s1 = 0.f, s2 = 0.f, s3 = 0.f;
        for (int j = 0; j < 128; j += 4) {
            s0 += p[(size_t)(j)     * (CLS * DIM)];
            s1 += p[(size_t)(j + 1) * (CLS * DIM)];
            s2 += p[(size_t)(j + 2) * (CLS * DIM)];
            s3 += p[(size_t)(j + 3) * (CLS * DIM)];
        }
        __shared__ float sh[4][64];
        sh[q][tid & 63] = (s0 + s1) + (s2 + s3);
        __syncthreads();
        if (tid < 64) fsum[o] = (sh[0][tid] + sh[1][tid]) + (sh[2][tid] + sh[3][tid]);
    } else {
        // counts: 64 outputs x NB partials
        const int c = tid & 63;
        const int q = tid >> 6;                       // 0..3
        int s = 0;
        for (int k = q * (NB / 4); k < (q + 1) * (NB / 4); ++k) s += pcnt[k * CLS + c];
        __shared__ int shc[4][64];
        shc[q][c] = s;
        __syncthreads();
        if (tid < 64) fcnt[tid] = (shc[0][tid] + shc[1][tid]) + (shc[2][tid] + shc[3][tid]);
        // sumsq: NB values, double, fixed order within lane then shuffle tree
        if (tid < 64) {
            double d = 0.0;
            for (int k = tid; k < NB; k += 64) d += (double)psq[k];
            for (int o2 = 32; o2 > 0; o2 >>= 1) d += __shfl_down(d, o2, 64);
            if (tid == 0) fsq[0] = d;
        }
    }
}

// ---------------- Phase C: centers, l2 identity, pairwise margin via Gram ----------------
__device__ double blockReduceD(double v, double* scratch, int tid) {
    for (int o = 32; o > 0; o >>= 1) v += __shfl_down(v, o, 64);
    if ((tid & 63) == 0) scratch[tid >> 6] = v;
    __syncthreads();
    double t = 0.0;
    if (tid == 0) {
        for (int i = 0; i < 16; ++i) t += scratch[i];
    }
    __syncthreads();
    return t;
}

__global__ __launch_bounds__(1024) void phaseC(const float* __restrict__ fsum,
                                               const int* __restrict__ fcnt,
                                               const double* __restrict__ fsq,
                                               float* __restrict__ out) {
    __shared__ float cenT[DIM][CLS];   // transposed centers: conflict-free column access
    __shared__ float nrm[CLS];
    __shared__ float cInv[CLS];
    __shared__ float cRaw[CLS];
    __shared__ double scratch[16];
    const int tid = threadIdx.x;

    if (tid < CLS) {
        float c = (float)fcnt[tid];
        cRaw[tid] = c;
        cInv[tid] = 1.f / (c + EPSF);
    }
    __syncthreads();

    double s1 = 0.0, s2 = 0.0;
    for (int i = tid; i < CLS * DIM; i += 1024) {
        const int c = i >> 7;
        const int d = i & 127;
        float v = fsum[i];
        float ctr = v * cInv[c];
        cenT[d][c] = ctr;
        s1 += (double)(v * ctr);
        s2 += (double)(cRaw[c] * ctr * ctr);
    }
    const double s1t = blockReduceD(s1, scratch, tid);   // internal syncs make cenT visible
    const double s2t = blockReduceD(s2, scratch, tid);

    // per-class squared norms
    if (tid < CLS) {
        float n = 0.f;
        for (int d = 0; d < DIM; ++d) {
            float v = cenT[d][tid];
            n += v * v;
        }
        nrm[tid] = n;
    }
    __syncthreads();

    // Gram: wave w handles rows a = w, w+16, w+32, w+48 against all b = lane
    const int w = tid >> 6;
    const int b = tid & 63;
    float g0 = 0.f, g1 = 0.f, g2 = 0.f, g3 = 0.f;
    for (int d = 0; d < DIM; ++d) {
        float vb = cenT[d][b];               // coalesced, conflict-free
        g0 += cenT[d][w]      * vb;          // wave-uniform -> broadcast
        g1 += cenT[d][w + 16] * vb;
        g2 += cenT[d][w + 32] * vb;
        g3 += cenT[d][w + 48] * vb;
    }
    float ccp = 0.f;
    {
        float gs[4] = {g0, g1, g2, g3};
#pragma unroll
        for (int j = 0; j < 4; ++j) {
            const int a = w + 16 * j;
            if (a == b) continue;
            float d2 = nrm[a] + nrm[b] - 2.f * gs[j];
            float val = fmaxf(MARGIN - sqrtf(fmaxf(d2, 0.f) + EPSF), 0.f);
            ccp += val * val;
        }
    }
    const double ccOrd = blockReduceD((double)ccp, scratch, tid);

    if (tid == 0) {
        double triu = ccOrd * 0.5;                     // ordered pairs -> a<b
        double ccv = triu / 64.0 * 63.0 / 2.0;
        double l2 = (fsq[0] - 2.0 * s1t + s2t) / (double)NROWS;
        out[0] = (float)(l2 + ccv);
    }
}

extern "C" void kernel_launch(void* const* d_in, const int* in_sizes, int n_in,
                              void* d_out, int out_size, void* d_ws, size_t ws_size,
                              hipStream_t stream) {
    const float* emb = (const float*)d_in[0];
    const int* tgt = (const int*)d_in[1];
    float* out = (float*)d_out;

    char* ws = (char*)d_ws;
    float* fsum = (float*)ws;                          // 8192 floats  @ 0
    int* fcnt = (int*)(ws + 32768);                    // 64 ints      @ 32768
    double* fsq = (double*)(ws + 33024);               // 1 double     @ 33024 (8-aligned)
    float* psum = (float*)(ws + 65536);                // NB*8192 floats (16 MB)
    int* pcnt = (int*)(ws + 65536 + (size_t)NB * CLS * DIM * 4);   // NB*64 ints
    float* psq = (float*)(ws + 65536 + (size_t)NB * CLS * DIM * 4 + (size_t)NB * CLS * 4); // NB floats

    const int rowsPerBlock = NROWS / NB;               // 512

    phaseA<<<NB, 1024, 0, stream>>>(emb, tgt, psum, pcnt, psq, rowsPerBlock);
    phaseBR<<<129, 256, 0, stream>>>(psum, pcnt, psq, fsum, fcnt, fsq);
    phaseC<<<1, 1024, 0, stream>>>(fsum, fcnt, fsq, out);
}